// Round 6
// baseline (10417.944 us; speedup 1.0000x reference)
//
#include <hip/hip_runtime.h>
#include <hip/hip_cooperative_groups.h>
#include <math.h>

namespace cg = cooperative_groups;

#define NB 128      // batch
#define NT 64       // timesteps
#define NI 512      // input dim
#define NH 1024     // hidden dim
#define NO 512      // output dim
#define PONDOFF (NB*NT*NO)

// dynamic LDS: [1024][32] w_hh column-slice, XOR-swizzled, 128 KB
extern __shared__ float smem[];

typedef float v4f __attribute__((ext_vector_type(4)));

// Device-coherent 16B load x4: bypasses L1+L2 (sc0 sc1), reads the coherence
// point (L3). Used ONLY for h data that crosses blocks -> no acquire fence /
// L2 invalidate needed anywhere, weights stay warm in L2.
__device__ __forceinline__ void ld4c(const float* p0, const float* p1,
                                     const float* p2, const float* p3,
                                     v4f& a, v4f& b, v4f& c, v4f& d)
{
    asm volatile(
        "global_load_dwordx4 %0, %4, off sc0 sc1\n\t"
        "global_load_dwordx4 %1, %5, off sc0 sc1\n\t"
        "global_load_dwordx4 %2, %6, off sc0 sc1\n\t"
        "global_load_dwordx4 %3, %7, off sc0 sc1\n\t"
        "s_waitcnt vmcnt(0)"
        : "=&v"(a), "=&v"(b), "=&v"(c), "=&v"(d)
        : "v"(p0), "v"(p1), "v"(p2), "v"(p3)
        : "memory");
}

// Per-group (32-block) barrier. Arrival: fetch_add(1, RELEASE) — the leader's
// release emits buffer_wbl2 on ITS XCD, flushing this block's dirty h lines
// to L3 (each of the 32 blocks does this). Poll: leader fetch_add(0) (RMW at
// coherence point = always fresh). NO acquire fence: readers use sc0/sc1
// coherent loads for cross-block data, so L2 is never invalidated.
__device__ __forceinline__ void group_barrier(unsigned* ctr, unsigned target, int tid)
{
    __syncthreads();   // all waves drain their stores to L2 before leader's wbl2
    if (tid == 0) {
        __hip_atomic_fetch_add(ctr, 1u, __ATOMIC_RELEASE, __HIP_MEMORY_SCOPE_AGENT);
        while (__hip_atomic_fetch_add(ctr, 0u, __ATOMIC_RELAXED,
                                      __HIP_MEMORY_SCOPE_AGENT) < target)
            __builtin_amdgcn_s_sleep(1);
    }
    __syncthreads();
}

// 256 blocks x 1024 threads. 8 groups x 32 blocks; group owns 16 batch rows,
// block owns a 32-col slice. Async row scheduling: every interval, every
// unfinished row executes one step (main or ponder) at its own timestep.
// All 32 blocks replicate the bit-identical decision state machine.
__global__ void __launch_bounds__(1024, 1)
arnn_coop(const float* __restrict__ x, const float* __restrict__ s0,
          const float* __restrict__ w_ih, const float* __restrict__ w_hh,
          const float* __restrict__ b_ih, const float* __restrict__ b_hh,
          const float* __restrict__ w_halt, const float* __restrict__ b_halt,
          const float* __restrict__ w_out, const float* __restrict__ b_out,
          float* __restrict__ out, float* __restrict__ ws)
{
    cg::grid_group grid = cg::this_grid();
    const int tid = threadIdx.x;
    const int bid = blockIdx.x;
    const int gid = bid * 1024 + tid;

    // ws layout (floats)
    float* wihT  = ws;                       // [NI][NH]  wihT[i*NH+j] = w_ih[j][1+i]
    float* hbuf  = wihT + NI*NH;             // [NB][2][NH] per-row ping-pong h
    float* habuf = hbuf + NB*2*NH;           // [2][NB][NH] timestep-parity h_acc
    unsigned* ctrA = (unsigned*)(habuf + 2*NB*NH);  // [8][16] arrival ctrs, 64B pad

    const int gp = bid >> 5, lb = bid & 31;

    __shared__ float s_whalt[NH];            // 4 KB
    // per-row replicated state (identical in all 32 blocks of the group)
    __shared__ int   s_t[16];
    __shared__ float s_cum[16];
    __shared__ int   s_n[16];
    __shared__ int   s_et[16], s_en[16];
    __shared__ unsigned char s_sl[16];
    __shared__ unsigned char s_run[16];
    __shared__ unsigned char s_mode[16];     // 0=main, 1=ponder (next step)
    __shared__ unsigned char s_epi[16];
    __shared__ int s_alive;

    // ---- phase 0 ----
    for (int e = gid; e < NI*NH; e += 256*1024) {
        const int i = e >> 10, jj = e & 1023;
        wihT[e] = w_ih[jj*(NI+1) + 1 + i];
    }
    if (gid < 8*16)
        __hip_atomic_store(&ctrA[gid], 0u, __ATOMIC_RELAXED, __HIP_MEMORY_SCOPE_AGENT);
    // stage this block's w_hh column slice into LDS, XOR-swizzled:
    // element (k, j) at float offset k*32 + ((j>>1)^((k>>6)&15))*2 + (j&1)
    for (int e = tid; e < 1024*32; e += 1024) {
        const int k = e & 1023, jj = e >> 10;
        const float v = w_hh[(lb*32 + jj)*NH + k];
        const int su = (jj >> 1) ^ ((k >> 6) & 15);
        smem[k*32 + su*2 + (jj & 1)] = v;
    }
    s_whalt[tid & 1023] = w_halt[tid & 1023];
    if (tid < 16) {
        s_t[tid] = 0; s_cum[tid] = 0.0f; s_n[tid] = 0;
        s_et[tid] = 0; s_en[tid] = 0;
        s_sl[tid] = 0; s_run[tid] = 1; s_mode[tid] = 0; s_epi[tid] = 0;
    }
    if (tid == 0) s_alive = 1;
    grid.sync();

    unsigned* ctr = ctrA + gp*16;

    const int w    = tid >> 6;
    const int lane = tid & 63;
    const int rq   = w >> 2;                 // row quad 0..3
    const int co   = w & 3;                  // col octet 0..3
    const int up   = lane & 3;               // col pair in octet
    const int ks   = lane >> 2;              // k-slice 0..15 (64 wide)
    const int u    = co*4 + up;              // col pair in block 0..15
    const int jg   = lb*32 + u*2;            // global col (pair base)
    const int b0   = gp*16 + rq*4;           // first of my 4 matmul rows
    const bool k0  = (ks == 0);
    const int ldsb = ks*2048 + ((u ^ ks) << 1);

    const float bh  = b_halt[0];
    const float bias0 = k0 ? (b_ih[jg]   + b_hh[jg])   : 0.0f;
    const float bias1 = k0 ? (b_ih[jg+1] + b_hh[jg+1]) : 0.0f;
    const float w0a   = k0 ? w_ih[jg*(NI+1)]     : 0.0f;
    const float w0b   = k0 ? w_ih[(jg+1)*(NI+1)] : 0.0f;

    // epilogue mapping: wave = row, lane = (ocol 0..15, kquarter 0..3)
    const int   eo = lb*16 + (lane & 15);
    const int   eq = lane >> 4;
    const int   eb = gp*16 + w;
    const float bo = b_out[eo];

    // decision mini-dot: wave w owns row gp*16+w; fixed tree = identical bits
    auto decide_p = [&](int slot) -> float {
        const float* hr = hbuf + ((gp*16 + w)*2 + slot)*NH + lane*16;
        v4f h0, h1, h2, h3;
        ld4c(hr, hr+4, hr+8, hr+12, h0, h1, h2, h3);
        const float4 w0 = *(const float4*)(&s_whalt[lane*16 + 0]);
        const float4 w1 = *(const float4*)(&s_whalt[lane*16 + 4]);
        const float4 w2 = *(const float4*)(&s_whalt[lane*16 + 8]);
        const float4 w3 = *(const float4*)(&s_whalt[lane*16 + 12]);
        float d = 0.0f;
        d += h0.x*w0.x + h0.y*w0.y + h0.z*w0.z + h0.w*w0.w;
        d += h1.x*w1.x + h1.y*w1.y + h1.z*w1.z + h1.w*w1.w;
        d += h2.x*w2.x + h2.y*w2.y + h2.z*w2.z + h2.w*w2.w;
        d += h3.x*w3.x + h3.y*w3.y + h3.z*w3.z + h3.w*w3.w;
        d += __shfl_xor(d, 1);  d += __shfl_xor(d, 2);  d += __shfl_xor(d, 4);
        d += __shfl_xor(d, 8);  d += __shfl_xor(d, 16); d += __shfl_xor(d, 32);
        return 1.0f / (1.0f + expf(-(d + bh)));
    };

    float xw[4][2];                          // per-row x-part, persists over ponder

    unsigned gen = 0;
    for (;;) {
        // ================= compute phase =================
        // ---- epilogue for my decide-row, if pending (h_acc via coherent loads) ----
        if (s_epi[w]) {
            const int et = s_et[w];
            const float* ha = habuf + (et&1)*(NB*NH) + eb*NH + eq*256;
            const float* wq = w_out + eo*NH + eq*256;
            float acc = 0.0f;
            for (int jj2 = 0; jj2 < 256; jj2 += 16) {
                v4f a0, a1, a2, a3;
                ld4c(ha+jj2, ha+jj2+4, ha+jj2+8, ha+jj2+12, a0, a1, a2, a3);
                const float4 q0 = *(const float4*)(wq + jj2);
                const float4 q1 = *(const float4*)(wq + jj2 + 4);
                const float4 q2 = *(const float4*)(wq + jj2 + 8);
                const float4 q3 = *(const float4*)(wq + jj2 + 12);
                acc += a0.x*q0.x + a0.y*q0.y + a0.z*q0.z + a0.w*q0.w;
                acc += a1.x*q1.x + a1.y*q1.y + a1.z*q1.z + a1.w*q1.w;
                acc += a2.x*q2.x + a2.y*q2.y + a2.z*q2.z + a2.w*q2.w;
                acc += a3.x*q3.x + a3.y*q3.y + a3.z*q3.z + a3.w*q3.w;
            }
            acc += __shfl_xor(acc, 16); acc += __shfl_xor(acc, 32);
            if (eq == 0) out[(eb*NT + et)*NO + eo] = acc + (float)s_en[w]*bo;
        }
        // ---- one step for each of my 4 matmul rows ----
        int ex[4], md[4], tt[4], sl[4];
        #pragma unroll
        for (int r = 0; r < 4; ++r) {
            const int rr = rq*4 + r;
            ex[r] = s_run[rr]; md[r] = s_mode[rr]; tt[r] = s_t[rr]; sl[r] = s_sl[rr];
        }
        const int mm0 = ex[0] & (md[0]==0), mm1 = ex[1] & (md[1]==0);
        const int mm2 = ex[2] & (md[2]==0), mm3 = ex[3] & (md[3]==0);
        if (mm0|mm1|mm2|mm3) {
            // merged x-part: weights loaded ONCE for all main-starting rows
            float o[4][2];
            o[0][0]=bias0; o[0][1]=bias1; o[1][0]=bias0; o[1][1]=bias1;
            o[2][0]=bias0; o[2][1]=bias1; o[3][0]=bias0; o[3][1]=bias1;
            const float* xr0 = x + ((b0+0)*NT + tt[0])*NI + ks*32;
            const float* xr1 = x + ((b0+1)*NT + tt[1])*NI + ks*32;
            const float* xr2 = x + ((b0+2)*NT + tt[2])*NI + ks*32;
            const float* xr3 = x + ((b0+3)*NT + tt[3])*NI + ks*32;
            const float* wp  = wihT + (ks*32)*NH + jg;
            #pragma unroll 4
            for (int i = 0; i < 32; i += 4) {
                const float4 x0 = *(const float4*)(xr0 + i);
                const float4 x1 = *(const float4*)(xr1 + i);
                const float4 x2 = *(const float4*)(xr2 + i);
                const float4 x3 = *(const float4*)(xr3 + i);
                const float2 wa = *(const float2*)(wp + (i  )*NH);
                const float2 wb = *(const float2*)(wp + (i+1)*NH);
                const float2 wc = *(const float2*)(wp + (i+2)*NH);
                const float2 wd = *(const float2*)(wp + (i+3)*NH);
                o[0][0] += x0.x*wa.x + x0.y*wb.x + x0.z*wc.x + x0.w*wd.x;
                o[0][1] += x0.x*wa.y + x0.y*wb.y + x0.z*wc.y + x0.w*wd.y;
                o[1][0] += x1.x*wa.x + x1.y*wb.x + x1.z*wc.x + x1.w*wd.x;
                o[1][1] += x1.x*wa.y + x1.y*wb.y + x1.z*wc.y + x1.w*wd.y;
                o[2][0] += x2.x*wa.x + x2.y*wb.x + x2.z*wc.x + x2.w*wd.x;
                o[2][1] += x2.x*wa.y + x2.y*wb.y + x2.z*wc.y + x2.w*wd.y;
                o[3][0] += x3.x*wa.x + x3.y*wb.x + x3.z*wc.x + x3.w*wd.x;
                o[3][1] += x3.x*wa.y + x3.y*wb.y + x3.z*wc.y + x3.w*wd.y;
            }
            if (mm0) { xw[0][0]=o[0][0]; xw[0][1]=o[0][1]; }
            if (mm1) { xw[1][0]=o[1][0]; xw[1][1]=o[1][1]; }
            if (mm2) { xw[2][0]=o[2][0]; xw[2][1]=o[2][1]; }
            if (mm3) { xw[3][0]=o[3][0]; xw[3][1]=o[3][1]; }
        }
        if (ex[0] | ex[1] | ex[2] | ex[3]) {
            // hh matmul: h via coherent loads; dead rows compute garbage (discarded)
            float a[4][2];
            const float* hp[4];
            #pragma unroll
            for (int r = 0; r < 4; ++r) {
                const int b = b0 + r;
                a[r][0] = xw[r][0] + (md[r] == 0 ? w0a : 0.0f);
                a[r][1] = xw[r][1] + (md[r] == 0 ? w0b : 0.0f);
                if (!ex[r])           hp[r] = hbuf + (b*2)*NH + ks*64;
                else if (md[r] == 0)  hp[r] = (tt[r] == 0 ? s0 + b*NH
                                              : habuf + ((tt[r]-1)&1)*(NB*NH) + b*NH) + ks*64;
                else                  hp[r] = hbuf + (b*2 + sl[r])*NH + ks*64;
            }
            for (int kc = 0; kc < 64; kc += 4) {
                v4f h0, h1, h2, h3;
                ld4c(hp[0]+kc, hp[1]+kc, hp[2]+kc, hp[3]+kc, h0, h1, h2, h3);
                const float2 wa = *(const float2*)(smem + ldsb + (kc  )*32);
                const float2 wb = *(const float2*)(smem + ldsb + (kc+1)*32);
                const float2 wc = *(const float2*)(smem + ldsb + (kc+2)*32);
                const float2 wd = *(const float2*)(smem + ldsb + (kc+3)*32);
                a[0][0] += h0.x*wa.x + h0.y*wb.x + h0.z*wc.x + h0.w*wd.x;
                a[0][1] += h0.x*wa.y + h0.y*wb.y + h0.z*wc.y + h0.w*wd.y;
                a[1][0] += h1.x*wa.x + h1.y*wb.x + h1.z*wc.x + h1.w*wd.x;
                a[1][1] += h1.x*wa.y + h1.y*wb.y + h1.z*wc.y + h1.w*wd.y;
                a[2][0] += h2.x*wa.x + h2.y*wb.x + h2.z*wc.x + h2.w*wd.x;
                a[2][1] += h2.x*wa.y + h2.y*wb.y + h2.z*wc.y + h2.w*wd.y;
                a[3][0] += h3.x*wa.x + h3.y*wb.x + h3.z*wc.x + h3.w*wd.x;
                a[3][1] += h3.x*wa.y + h3.y*wb.y + h3.z*wc.y + h3.w*wd.y;
            }
            #pragma unroll
            for (int r = 0; r < 4; ++r)
                #pragma unroll
                for (int c = 0; c < 2; ++c) {
                    float v = a[r][c];
                    v += __shfl_xor(v, 4);  v += __shfl_xor(v, 8);
                    v += __shfl_xor(v, 16); v += __shfl_xor(v, 32);
                    a[r][c] = v;
                }
            if (k0) {
                #pragma unroll
                for (int r = 0; r < 4; ++r) {
                    if (ex[r]) {
                        const float ha = tanhf(a[r][0]), hb = tanhf(a[r][1]);
                        const int b = b0 + r;
                        float* hw = hbuf + (b*2 + (sl[r]^1))*NH + jg;
                        hw[0] = ha; hw[1] = hb;
                        float* hq = habuf + (tt[r]&1)*(NB*NH) + b*NH + jg;
                        if (md[r] == 0) { hq[0] = ha;  hq[1] = hb;  }
                        else            { hq[0] += ha; hq[1] += hb; }
                    }
                }
            }
        }
        // ================= barrier =================
        ++gen; group_barrier(ctr, 32*gen, tid);
        // ================= decide + state update (row w, bit-identical) ========
        const int exw = s_run[w];
        float p = 0.0f;
        if (exw) p = decide_p(s_sl[w] ^ 1);
        if (lane == 0) {
            int newepi = 0;
            if (exw) {
                const int t = s_t[w];
                float cum; int n;
                if (s_mode[w] == 0) {
                    cum = p; n = 1;
                    if (lb == 0) out[PONDOFF + (gp*16 + w)*NT + t] = (p >= 0.99f) ? 2.0f : 0.0f;
                } else {
                    cum = s_cum[w] + p; n = s_n[w] + 1;
                }
                s_cum[w] = cum; s_n[w] = n;
                s_sl[w] ^= 1;
                if ((cum < 0.99f) && n < 12) {
                    s_mode[w] = 1;
                } else {                     // timestep finished
                    newepi = 1; s_et[w] = t; s_en[w] = n;
                    if (t == NT-1) s_run[w] = 0;
                    else { s_t[w] = t + 1; s_mode[w] = 0; }
                }
            }
            s_epi[w] = newepi;
        }
        __syncthreads();
        if (w == 0) {
            const int al = (lane < 16) ? (s_run[lane] | s_epi[lane]) : 0;
            const unsigned long long m = __ballot(al);
            if (lane == 0) s_alive = (m != 0ULL) ? 1 : 0;
        }
        __syncthreads();
        if (!s_alive) break;
    }
}

extern "C" void kernel_launch(void* const* d_in, const int* in_sizes, int n_in,
                              void* d_out, int out_size, void* d_ws, size_t ws_size,
                              hipStream_t stream) {
    const float* x      = (const float*)d_in[0];
    const float* s0     = (const float*)d_in[1];
    const float* w_ih   = (const float*)d_in[2];
    const float* w_hh   = (const float*)d_in[3];
    const float* b_ih   = (const float*)d_in[4];
    const float* b_hh   = (const float*)d_in[5];
    const float* w_halt = (const float*)d_in[6];
    const float* b_halt = (const float*)d_in[7];
    const float* w_out  = (const float*)d_in[8];
    const float* b_out  = (const float*)d_in[9];
    float* out = (float*)d_out;
    float* ws  = (float*)d_ws;

    static const int kLds = 131072;
    hipFuncSetAttribute((const void*)arnn_coop,
                        hipFuncAttributeMaxDynamicSharedMemorySize, kLds);

    void* args[] = { (void*)&x, (void*)&s0, (void*)&w_ih, (void*)&w_hh,
                     (void*)&b_ih, (void*)&b_hh, (void*)&w_halt, (void*)&b_halt,
                     (void*)&w_out, (void*)&b_out, (void*)&out, (void*)&ws };
    hipLaunchCooperativeKernel((void*)arnn_coop, dim3(256), dim3(1024), args, kLds, stream);
}

// Round 7
// 9767.191 us; speedup vs baseline: 1.0666x; 1.0666x over previous
//
#include <hip/hip_runtime.h>
#include <hip/hip_cooperative_groups.h>
#include <math.h>

namespace cg = cooperative_groups;

#define NB 128      // batch
#define NT 64       // timesteps
#define NI 512      // input dim
#define NH 1024     // hidden dim
#define NO 512      // output dim
#define PONDOFF (NB*NT*NO)

// dynamic LDS: [1024][32] w_hh column-slice, ADD-swizzled, 128 KB
extern __shared__ float smem[];

typedef float v4f __attribute__((ext_vector_type(4)));
typedef float v2f __attribute__((ext_vector_type(2)));

// ---- coherent (coherence-point) memory ops: sc0 sc1 = bypass L1/L2.
// All cross-block data uses these for BOTH read and write -> no buffer_wbl2,
// no buffer_inv, no release/acquire cache maintenance ANYWHERE in the loop.
__device__ __forceinline__ void st2c(float* p, float a, float b) {
    v2f v; v.x = a; v.y = b;
    asm volatile("global_store_dwordx2 %0, %1, off sc0 sc1" :: "v"(p), "v"(v) : "memory");
}
__device__ __forceinline__ void st1c(float* p, float v) {
    asm volatile("global_store_dword %0, %1, off sc0 sc1" :: "v"(p), "v"(v) : "memory");
}
__device__ __forceinline__ void st1u(unsigned* p, unsigned v) {
    asm volatile("global_store_dword %0, %1, off sc0 sc1" :: "v"(p), "v"(v) : "memory");
}
__device__ __forceinline__ unsigned ld1u(const unsigned* p) {
    unsigned r;
    asm volatile("global_load_dword %0, %1, off sc0 sc1\n\ts_waitcnt vmcnt(0)"
                 : "=&v"(r) : "v"(p) : "memory");
    return r;
}
__device__ __forceinline__ v4f ld4d(const float* p) {
    v4f r;
    asm volatile("global_load_dwordx4 %0, %1, off sc0 sc1\n\ts_waitcnt vmcnt(0)"
                 : "=&v"(r) : "v"(p) : "memory");
    return r;
}
// 16 coherent dwordx4 loads (4 bases x offsets 0/16/32/48 B), ONE wait.
__device__ __forceinline__ void ld16c(const float* p0, const float* p1,
                                      const float* p2, const float* p3,
                                      v4f& h00, v4f& h01, v4f& h02, v4f& h03,
                                      v4f& h10, v4f& h11, v4f& h12, v4f& h13,
                                      v4f& h20, v4f& h21, v4f& h22, v4f& h23,
                                      v4f& h30, v4f& h31, v4f& h32, v4f& h33)
{
    asm volatile(
        "global_load_dwordx4 %0, %16, off sc0 sc1\n\t"
        "global_load_dwordx4 %1, %16, off offset:16 sc0 sc1\n\t"
        "global_load_dwordx4 %2, %16, off offset:32 sc0 sc1\n\t"
        "global_load_dwordx4 %3, %16, off offset:48 sc0 sc1\n\t"
        "global_load_dwordx4 %4, %17, off sc0 sc1\n\t"
        "global_load_dwordx4 %5, %17, off offset:16 sc0 sc1\n\t"
        "global_load_dwordx4 %6, %17, off offset:32 sc0 sc1\n\t"
        "global_load_dwordx4 %7, %17, off offset:48 sc0 sc1\n\t"
        "global_load_dwordx4 %8, %18, off sc0 sc1\n\t"
        "global_load_dwordx4 %9, %18, off offset:16 sc0 sc1\n\t"
        "global_load_dwordx4 %10, %18, off offset:32 sc0 sc1\n\t"
        "global_load_dwordx4 %11, %18, off offset:48 sc0 sc1\n\t"
        "global_load_dwordx4 %12, %19, off sc0 sc1\n\t"
        "global_load_dwordx4 %13, %19, off offset:16 sc0 sc1\n\t"
        "global_load_dwordx4 %14, %19, off offset:32 sc0 sc1\n\t"
        "global_load_dwordx4 %15, %19, off offset:48 sc0 sc1\n\t"
        "s_waitcnt vmcnt(0)"
        : "=&v"(h00), "=&v"(h01), "=&v"(h02), "=&v"(h03),
          "=&v"(h10), "=&v"(h11), "=&v"(h12), "=&v"(h13),
          "=&v"(h20), "=&v"(h21), "=&v"(h22), "=&v"(h23),
          "=&v"(h30), "=&v"(h31), "=&v"(h32), "=&v"(h33)
        : "v"(p0), "v"(p1), "v"(p2), "v"(p3)
        : "memory");
}

// Per-group barrier v4: arrival = RELAXED fetch_add (safe: __syncthreads has
// already drained every wave's vmcnt, and all data stores are sc1
// write-through -> already at the coherence point). The LAST arriver knows
// instantly from its returned count and broadcasts GO (sc1 store); everyone
// else polls GO with sc1 LOADS (no RMW serialization, no cache ops).
__device__ __forceinline__ void group_barrier(unsigned* ctr, unsigned* go,
                                              unsigned gen, int tid)
{
    __syncthreads();
    if (tid == 0) {
        const unsigned old = __hip_atomic_fetch_add(ctr, 1u, __ATOMIC_RELAXED,
                                                    __HIP_MEMORY_SCOPE_AGENT);
        if (old == 32u*gen - 1u) {
            st1u(go, gen);
        } else {
            while (ld1u(go) < gen) __builtin_amdgcn_s_sleep(4);
        }
    }
    __syncthreads();
}

// 256 blocks x 1024 threads. 8 groups x 32 blocks; group owns 16 batch rows,
// block owns a 32-col slice. Async row scheduling (every live row does one
// step per interval at its own timestep). Decisions from per-block halt
// PARTIALS summed in a fixed tree -> bit-identical in all 32 blocks.
__global__ void __launch_bounds__(1024, 1)
arnn_coop(const float* __restrict__ x, const float* __restrict__ s0,
          const float* __restrict__ w_ih, const float* __restrict__ w_hh,
          const float* __restrict__ b_ih, const float* __restrict__ b_hh,
          const float* __restrict__ w_halt, const float* __restrict__ b_halt,
          const float* __restrict__ w_out, const float* __restrict__ b_out,
          float* __restrict__ out, float* __restrict__ ws)
{
    cg::grid_group grid = cg::this_grid();
    const int tid = threadIdx.x;
    const int bid = blockIdx.x;
    const int gid = bid * 1024 + tid;

    // ws layout (floats)
    float* wihT  = ws;                          // [NI][NH]
    float* hbuf  = wihT + NI*NH;                // [NB][2][NH] per-row ping-pong h
    float* habuf = hbuf + NB*2*NH;              // [2][NB][NH] running h_acc (parity)
    float* part  = habuf + 2*NB*NH;             // [128 rows][128] halt partials
    unsigned* ctrA = (unsigned*)(part + NB*128);   // [8][64]  (256B stride)
    unsigned* goA  = ctrA + 8*64;                  // [8][64]

    const int gp = bid >> 5, lb = bid & 31;

    // per-row replicated state (identical across the group's 32 blocks)
    __shared__ int   s_t[16];
    __shared__ float s_cum[16];
    __shared__ int   s_n[16];
    __shared__ int   s_et[16], s_en[16];
    __shared__ unsigned char s_sl[16];
    __shared__ unsigned char s_run[16];
    __shared__ unsigned char s_mode[16];        // 0=main, 1=ponder (next step)
    __shared__ unsigned char s_epi[16];
    __shared__ int s_alive;

    // ---- phase 0 ----
    for (int e = gid; e < NI*NH; e += 256*1024) {
        const int i = e >> 10, jj = e & 1023;
        wihT[e] = w_ih[jj*(NI+1) + 1 + i];
    }
    if (gid < 2*8*64) ctrA[gid] = 0u;
    // stage w_hh column slice into LDS, ADD-swizzled:
    // (k, j): slot = ((j>>1) + 4*(k>>6)) & 15; ofs = k*32 + slot*2 + (j&1)
    // -> per half-wave read pattern hits every bank-pair exactly 2x (floor).
    for (int e = tid; e < 1024*32; e += 1024) {
        const int k = e & 1023, jj = e >> 10;
        const float v = w_hh[(lb*32 + jj)*NH + k];
        const int slot = ((jj >> 1) + 4*(k >> 6)) & 15;
        smem[k*32 + slot*2 + (jj & 1)] = v;
    }
    if (tid < 16) {
        s_t[tid] = 0; s_cum[tid] = 0.0f; s_n[tid] = 0;
        s_et[tid] = 0; s_en[tid] = 0;
        s_sl[tid] = 0; s_run[tid] = 1; s_mode[tid] = 0; s_epi[tid] = 0;
    }
    if (tid == 0) s_alive = 1;
    grid.sync();

    unsigned* ctr = ctrA + gp*64;
    unsigned* go  = goA  + gp*64;

    const int w    = tid >> 6;
    const int lane = tid & 63;
    const int rq   = w >> 2;                 // row quad 0..3
    const int co   = w & 3;                  // col octet 0..3
    const int up   = lane & 3;               // col pair in octet
    const int ks   = lane >> 2;              // k-slice 0..15 (64 wide)
    const int u    = co*4 + up;              // col pair in block 0..15
    const int jg   = lb*32 + u*2;            // global col (pair base)
    const int b0   = gp*16 + rq*4;           // first of my 4 matmul rows
    const bool k0  = (ks == 0);
    const int ldsb = ks*2048 + (((u + 4*ks) & 15) << 1);

    const float bh  = b_halt[0];
    const float wh0 = w_halt[jg], wh1 = w_halt[jg+1];
    const float bias0 = k0 ? (b_ih[jg]   + b_hh[jg])   : 0.0f;
    const float bias1 = k0 ? (b_ih[jg+1] + b_hh[jg+1]) : 0.0f;
    const float w0a   = k0 ? w_ih[jg*(NI+1)]     : 0.0f;
    const float w0b   = k0 ? w_ih[(jg+1)*(NI+1)] : 0.0f;

    // epilogue mapping: wave = row, lane = (ocol 0..15, kquarter 0..3)
    const int   eo = lb*16 + (lane & 15);
    const int   eq = lane >> 4;
    const int   eb = gp*16 + w;
    const float bo = b_out[eo];

    float xw[4][2];        // per-row x-part partials (persist over ponder)
    float hacc[4][2];      // running h_acc slice (valid on k0 lanes)

    unsigned gen = 0;
    for (;;) {
        // ================= compute phase =================
        // ---- row states for my quad
        int ex[4], md[4], tt[4], sl[4];
        #pragma unroll
        for (int r = 0; r < 4; ++r) {
            const int rr = rq*4 + r;
            ex[r] = s_run[rr]; md[r] = s_mode[rr]; tt[r] = s_t[rr]; sl[r] = s_sl[rr];
        }
        // ---- epilogue for row w if pending (reads habuf written last interval)
        if (s_epi[w]) {
            const int et = s_et[w];
            const float* ha = habuf + (et&1)*(NB*NH) + eb*NH + eq*256;
            const float* wq = w_out + eo*NH + eq*256;
            float acc = 0.0f;
            #pragma unroll
            for (int c = 0; c < 4; ++c) {
                v4f e0,e1,e2,e3,e4,e5,e6,e7,e8,e9,ea,eb2,ec,ed,ee,ef;
                const float* hb2 = ha + c*64;
                ld16c(hb2, hb2+16, hb2+32, hb2+48,
                      e0,e1,e2,e3,e4,e5,e6,e7,e8,e9,ea,eb2,ec,ed,ee,ef);
                const float* wv = wq + c*64;
                acc += e0.x*wv[0]+e0.y*wv[1]+e0.z*wv[2]+e0.w*wv[3]
                     + e1.x*wv[4]+e1.y*wv[5]+e1.z*wv[6]+e1.w*wv[7]
                     + e2.x*wv[8]+e2.y*wv[9]+e2.z*wv[10]+e2.w*wv[11]
                     + e3.x*wv[12]+e3.y*wv[13]+e3.z*wv[14]+e3.w*wv[15];
                acc += e4.x*wv[16]+e4.y*wv[17]+e4.z*wv[18]+e4.w*wv[19]
                     + e5.x*wv[20]+e5.y*wv[21]+e5.z*wv[22]+e5.w*wv[23]
                     + e6.x*wv[24]+e6.y*wv[25]+e6.z*wv[26]+e6.w*wv[27]
                     + e7.x*wv[28]+e7.y*wv[29]+e7.z*wv[30]+e7.w*wv[31];
                acc += e8.x*wv[32]+e8.y*wv[33]+e8.z*wv[34]+e8.w*wv[35]
                     + e9.x*wv[36]+e9.y*wv[37]+e9.z*wv[38]+e9.w*wv[39]
                     + ea.x*wv[40]+ea.y*wv[41]+ea.z*wv[42]+ea.w*wv[43]
                     + eb2.x*wv[44]+eb2.y*wv[45]+eb2.z*wv[46]+eb2.w*wv[47];
                acc += ec.x*wv[48]+ec.y*wv[49]+ec.z*wv[50]+ec.w*wv[51]
                     + ed.x*wv[52]+ed.y*wv[53]+ed.z*wv[54]+ed.w*wv[55]
                     + ee.x*wv[56]+ee.y*wv[57]+ee.z*wv[58]+ee.w*wv[59]
                     + ef.x*wv[60]+ef.y*wv[61]+ef.z*wv[62]+ef.w*wv[63];
            }
            acc += __shfl_xor(acc, 16); acc += __shfl_xor(acc, 32);
            if (eq == 0) st1c(&out[(eb*NT + et)*NO + eo], acc + (float)s_en[w]*bo);
        }
        // ---- x-part for rows starting a timestep (weights loaded once)
        const int mm0 = ex[0]&(md[0]==0), mm1 = ex[1]&(md[1]==0);
        const int mm2 = ex[2]&(md[2]==0), mm3 = ex[3]&(md[3]==0);
        if (mm0|mm1|mm2|mm3) {
            float o[4][2];
            o[0][0]=bias0; o[0][1]=bias1; o[1][0]=bias0; o[1][1]=bias1;
            o[2][0]=bias0; o[2][1]=bias1; o[3][0]=bias0; o[3][1]=bias1;
            const float* xr0 = x + ((b0+0)*NT + tt[0])*NI + ks*32;
            const float* xr1 = x + ((b0+1)*NT + tt[1])*NI + ks*32;
            const float* xr2 = x + ((b0+2)*NT + tt[2])*NI + ks*32;
            const float* xr3 = x + ((b0+3)*NT + tt[3])*NI + ks*32;
            const float* wp  = wihT + (ks*32)*NH + jg;
            #pragma unroll 4
            for (int i = 0; i < 32; i += 4) {
                const float4 x0 = *(const float4*)(xr0 + i);
                const float4 x1 = *(const float4*)(xr1 + i);
                const float4 x2 = *(const float4*)(xr2 + i);
                const float4 x3 = *(const float4*)(xr3 + i);
                const float2 wa = *(const float2*)(wp + (i  )*NH);
                const float2 wb = *(const float2*)(wp + (i+1)*NH);
                const float2 wc = *(const float2*)(wp + (i+2)*NH);
                const float2 wd = *(const float2*)(wp + (i+3)*NH);
                o[0][0] += x0.x*wa.x + x0.y*wb.x + x0.z*wc.x + x0.w*wd.x;
                o[0][1] += x0.x*wa.y + x0.y*wb.y + x0.z*wc.y + x0.w*wd.y;
                o[1][0] += x1.x*wa.x + x1.y*wb.x + x1.z*wc.x + x1.w*wd.x;
                o[1][1] += x1.x*wa.y + x1.y*wb.y + x1.z*wc.y + x1.w*wd.y;
                o[2][0] += x2.x*wa.x + x2.y*wb.x + x2.z*wc.x + x2.w*wd.x;
                o[2][1] += x2.x*wa.y + x2.y*wb.y + x2.z*wc.y + x2.w*wd.y;
                o[3][0] += x3.x*wa.x + x3.y*wb.x + x3.z*wc.x + x3.w*wd.x;
                o[3][1] += x3.x*wa.y + x3.y*wb.y + x3.z*wc.y + x3.w*wd.y;
            }
            if (mm0) { xw[0][0]=o[0][0]; xw[0][1]=o[0][1]; }
            if (mm1) { xw[1][0]=o[1][0]; xw[1][1]=o[1][1]; }
            if (mm2) { xw[2][0]=o[2][0]; xw[2][1]=o[2][1]; }
            if (mm3) { xw[3][0]=o[3][0]; xw[3][1]=o[3][1]; }
        }
        // ---- one hh step for the quad (dead rows compute garbage, discarded)
        if (ex[0]|ex[1]|ex[2]|ex[3]) {
            float a[4][2];
            const float* hp[4];
            #pragma unroll
            for (int r = 0; r < 4; ++r) {
                const int b = b0 + r;
                a[r][0] = xw[r][0] + (md[r]==0 ? w0a : 0.0f);
                a[r][1] = xw[r][1] + (md[r]==0 ? w0b : 0.0f);
                if (!ex[r])          hp[r] = hbuf + (b*2)*NH + ks*64;
                else if (md[r]==0)   hp[r] = (tt[r]==0 ? s0 + b*NH
                                             : habuf + ((tt[r]-1)&1)*(NB*NH) + b*NH) + ks*64;
                else                 hp[r] = hbuf + (b*2 + sl[r])*NH + ks*64;
            }
            #pragma unroll
            for (int kq = 0; kq < 4; ++kq) {
                v4f h00,h01,h02,h03,h10,h11,h12,h13,h20,h21,h22,h23,h30,h31,h32,h33;
                ld16c(hp[0]+kq*16, hp[1]+kq*16, hp[2]+kq*16, hp[3]+kq*16,
                      h00,h01,h02,h03,h10,h11,h12,h13,h20,h21,h22,h23,h30,h31,h32,h33);
                const float* wbase = smem + ldsb + (kq*16)*32;
                #pragma unroll
                for (int q = 0; q < 4; ++q) {
                    const float2 wa = *(const float2*)(wbase + (q*4  )*32);
                    const float2 wb2= *(const float2*)(wbase + (q*4+1)*32);
                    const float2 wc = *(const float2*)(wbase + (q*4+2)*32);
                    const float2 wd = *(const float2*)(wbase + (q*4+3)*32);
                    const v4f hq0 = (q==0)?h00:(q==1)?h01:(q==2)?h02:h03;
                    const v4f hq1 = (q==0)?h10:(q==1)?h11:(q==2)?h12:h13;
                    const v4f hq2 = (q==0)?h20:(q==1)?h21:(q==2)?h22:h23;
                    const v4f hq3 = (q==0)?h30:(q==1)?h31:(q==2)?h32:h33;
                    a[0][0] += hq0.x*wa.x + hq0.y*wb2.x + hq0.z*wc.x + hq0.w*wd.x;
                    a[0][1] += hq0.x*wa.y + hq0.y*wb2.y + hq0.z*wc.y + hq0.w*wd.y;
                    a[1][0] += hq1.x*wa.x + hq1.y*wb2.x + hq1.z*wc.x + hq1.w*wd.x;
                    a[1][1] += hq1.x*wa.y + hq1.y*wb2.y + hq1.z*wc.y + hq1.w*wd.y;
                    a[2][0] += hq2.x*wa.x + hq2.y*wb2.x + hq2.z*wc.x + hq2.w*wd.x;
                    a[2][1] += hq2.x*wa.y + hq2.y*wb2.y + hq2.z*wc.y + hq2.w*wd.y;
                    a[3][0] += hq3.x*wa.x + hq3.y*wb2.x + hq3.z*wc.x + hq3.w*wd.x;
                    a[3][1] += hq3.x*wa.y + hq3.y*wb2.y + hq3.z*wc.y + hq3.w*wd.y;
                }
            }
            #pragma unroll
            for (int r = 0; r < 4; ++r)
                #pragma unroll
                for (int c = 0; c < 2; ++c) {
                    float v = a[r][c];
                    v += __shfl_xor(v, 4);  v += __shfl_xor(v, 8);
                    v += __shfl_xor(v, 16); v += __shfl_xor(v, 32);
                    a[r][c] = v;
                }
            // h, halt partial, h_acc (write-through; regs hold h_acc)
            float pr[4];
            #pragma unroll
            for (int r = 0; r < 4; ++r) {
                const float ha = tanhf(a[r][0]), hb2 = tanhf(a[r][1]);
                pr[r] = ha*wh0 + hb2*wh1;
                if (k0 && ex[r]) {
                    const int b = b0 + r;
                    st2c(hbuf + (b*2 + (sl[r]^1))*NH + jg, ha, hb2);
                    if (md[r] == 0) { hacc[r][0] = ha;  hacc[r][1] = hb2; }
                    else            { hacc[r][0] += ha; hacc[r][1] += hb2; }
                    st2c(habuf + (tt[r]&1)*(NB*NH) + b*NH + jg, hacc[r][0], hacc[r][1]);
                }
            }
            #pragma unroll
            for (int r = 0; r < 4; ++r) {
                pr[r] += __shfl_xor(pr[r], 1);
                pr[r] += __shfl_xor(pr[r], 2);
            }
            if (lane == 0) {
                #pragma unroll
                for (int r = 0; r < 4; ++r)
                    if (ex[r]) st1c(&part[(gp*16 + rq*4 + r)*128 + lb*4 + co], pr[r]);
            }
        }
        // ================= barrier =================
        ++gen; group_barrier(ctr, go, gen, tid);
        // ================= decide (row w, bit-identical everywhere) ============
        const int exw = s_run[w];
        float psum = 0.0f;
        if (exw) {
            const v4f pv = ld4d(part + (gp*16 + w)*128 + (lane & 31)*4);
            psum = (pv.x + pv.y) + (pv.z + pv.w);
            psum += __shfl_xor(psum, 1); psum += __shfl_xor(psum, 2);
            psum += __shfl_xor(psum, 4); psum += __shfl_xor(psum, 8);
            psum += __shfl_xor(psum, 16);
        }
        if (lane == 0) {
            int ne = 0;
            if (exw) {
                const float p = 1.0f / (1.0f + expf(-(psum + bh)));
                const int t = s_t[w];
                float cum; int n;
                if (s_mode[w] == 0) {
                    cum = p; n = 1;
                    if (lb == 0) st1c(&out[PONDOFF + (gp*16 + w)*NT + t],
                                      (p >= 0.99f) ? 2.0f : 0.0f);
                } else {
                    cum = s_cum[w] + p; n = s_n[w] + 1;
                }
                s_cum[w] = cum; s_n[w] = n;
                s_sl[w] ^= 1;
                if (cum < 0.99f && n < 12) {
                    s_mode[w] = 1;
                } else {
                    ne = 1; s_et[w] = t; s_en[w] = n;
                    if (t == NT-1) s_run[w] = 0;
                    else { s_t[w] = t + 1; s_mode[w] = 0; }
                }
            }
            s_epi[w] = ne;
        }
        __syncthreads();
        if (w == 0) {
            const int al = (lane < 16) ? (s_run[lane] | s_epi[lane]) : 0;
            const unsigned long long m = __ballot(al);
            if (lane == 0) s_alive = (m != 0ULL) ? 1 : 0;
        }
        __syncthreads();
        if (!s_alive) break;
    }
}

extern "C" void kernel_launch(void* const* d_in, const int* in_sizes, int n_in,
                              void* d_out, int out_size, void* d_ws, size_t ws_size,
                              hipStream_t stream) {
    const float* x      = (const float*)d_in[0];
    const float* s0     = (const float*)d_in[1];
    const float* w_ih   = (const float*)d_in[2];
    const float* w_hh   = (const float*)d_in[3];
    const float* b_ih   = (const float*)d_in[4];
    const float* b_hh   = (const float*)d_in[5];
    const float* w_halt = (const float*)d_in[6];
    const float* b_halt = (const float*)d_in[7];
    const float* w_out  = (const float*)d_in[8];
    const float* b_out  = (const float*)d_in[9];
    float* out = (float*)d_out;
    float* ws  = (float*)d_ws;

    static const int kLds = 131072;
    hipFuncSetAttribute((const void*)arnn_coop,
                        hipFuncAttributeMaxDynamicSharedMemorySize, kLds);

    void* args[] = { (void*)&x, (void*)&s0, (void*)&w_ih, (void*)&w_hh,
                     (void*)&b_ih, (void*)&b_hh, (void*)&w_halt, (void*)&b_halt,
                     (void*)&w_out, (void*)&b_out, (void*)&out, (void*)&ws };
    hipLaunchCooperativeKernel((void*)arnn_coop, dim3(256), dim3(1024), args, kLds, stream);
}